// Round 20
// baseline (200.657 us; speedup 1.0000x reference)
//
#include <hip/hip_runtime.h>
#include <math.h>

#define NBF 4104             // B*F = 8*513
#define XT_FLOATS 16809984   // 8*513*8*512

// Static device scratch; fully overwritten before read each call -> deterministic.
__device__ float  d_partials[NBF];
__device__ float2 d_Qc[NBF * 64];   // full complex Q (g_out only holds Re in qmode=1)

// Phase-A macros over float4 components (r17's proven form: wave g owns row-pair
// {g,7-g}, 9 Hermitian entries, 16 accumulator floats -> VGPR 68, no spill).
#define PA_CROSS(P,N,C) cr[P] += ar*xr4[N].C + ai*xi4[N].C; \
                        ci[P] += ai*xr4[N].C - ar*xi4[N].C;

#define PA_G0(C) { const float rw = fmaxf(rv.C, 1e-3f); float ar, ai;          \
    ar = rw*xr4[0].C; ai = rw*xi4[0].C; d0 += ar*xr4[0].C + ai*xi4[0].C;       \
    PA_CROSS(0,1,C) PA_CROSS(1,2,C) PA_CROSS(2,3,C) PA_CROSS(3,4,C)            \
    PA_CROSS(4,5,C) PA_CROSS(5,6,C) PA_CROSS(6,7,C)                            \
    ar = rw*xr4[7].C; ai = rw*xi4[7].C; d1 += ar*xr4[7].C + ai*xi4[7].C; }

#define PA_G1(C) { const float rw = fmaxf(rv.C, 1e-3f); float ar, ai;          \
    ar = rw*xr4[1].C; ai = rw*xi4[1].C; d0 += ar*xr4[1].C + ai*xi4[1].C;       \
    PA_CROSS(0,2,C) PA_CROSS(1,3,C) PA_CROSS(2,4,C) PA_CROSS(3,5,C)            \
    PA_CROSS(4,6,C) PA_CROSS(5,7,C)                                            \
    ar = rw*xr4[6].C; ai = rw*xi4[6].C; d1 += ar*xr4[6].C + ai*xi4[6].C;       \
    PA_CROSS(6,7,C) }

#define PA_G2(C) { const float rw = fmaxf(rv.C, 1e-3f); float ar, ai;          \
    ar = rw*xr4[2].C; ai = rw*xi4[2].C; d0 += ar*xr4[2].C + ai*xi4[2].C;       \
    PA_CROSS(0,3,C) PA_CROSS(1,4,C) PA_CROSS(2,5,C) PA_CROSS(3,6,C)            \
    PA_CROSS(4,7,C)                                                            \
    ar = rw*xr4[5].C; ai = rw*xi4[5].C; d1 += ar*xr4[5].C + ai*xi4[5].C;       \
    PA_CROSS(5,6,C) PA_CROSS(6,7,C) }

#define PA_G3(C) { const float rw = fmaxf(rv.C, 1e-3f); float ar, ai;          \
    ar = rw*xr4[3].C; ai = rw*xi4[3].C; d0 += ar*xr4[3].C + ai*xi4[3].C;       \
    PA_CROSS(0,4,C) PA_CROSS(1,5,C) PA_CROSS(2,6,C) PA_CROSS(3,7,C)            \
    ar = rw*xr4[4].C; ai = rw*xi4[4].C; d1 += ar*xr4[4].C + ai*xi4[4].C;       \
    PA_CROSS(4,5,C) PA_CROSS(5,6,C) PA_CROSS(6,7,C) }

#define VSTD2(D,M)  s_V[k][M][M] = make_float2((D)*invT, 0.f);
#define VSTO2(P,M,N){ const float vr=cr[P]*invT, vi=ci[P]*invT;  \
                      s_V[k][M][N] = make_float2(vr,  vi);       \
                      s_V[k][N][M] = make_float2(vr, -vi); }

// EXACT r17 structure (best measured: 193.7 us total). r18 (32-acc split) and
// r19 (fused C-lite) both regressed: register pressure kills load-hoisting,
// and the post-phase-B barrier serializes waves that r17 lets exit early.
__global__ __launch_bounds__(256, 2) void iss_cov(
    const float* __restrict__ g_r,
    const float* __restrict__ g_xre,
    const float* __restrict__ g_xim,
    const float* __restrict__ g_Qre,
    const float* __restrict__ g_Qim,
    float* __restrict__ g_out,
    const int qmode)
{
    __shared__ float  s_xr[8][512];    // 16 KB
    __shared__ float  s_xi[8][512];    // 16 KB
    __shared__ float2 s_V[8][8][9];    // padded row stride
    __shared__ float2 s_Q[8][8];

    const int tid = threadIdx.x;
    const int bf  = blockIdx.x;
    const size_t base = (size_t)bf * 4096;

    const float* xre = g_xre + base;
    const float* xim = g_xim + base;

    // ---- stage x into LDS (float4 loads + b128 writes, fully coalesced) ----
    {
        const float4* xr4g = (const float4*)xre;
        const float4* xi4g = (const float4*)xim;
        float4* sxr4 = (float4*)&s_xr[0][0];
        float4* sxi4 = (float4*)&s_xi[0][0];
        #pragma unroll
        for (int i = 0; i < 4; ++i) {
            const int idx = tid + (i << 8);
            sxr4[idx] = xr4g[idx];
            sxi4[idx] = xi4g[idx];
        }
        if (tid < 64)
            s_Q[tid>>3][tid&7] = make_float2(g_Qre[(size_t)bf*64 + tid],
                                             g_Qim[(size_t)bf*64 + tid]);
    }
    __syncthreads();

    // ---- phase A: V[k] = (1/T) sum_t max(r,1e-3) x x^H -------------------
    const int tl = tid & 7;
    const int k  = (tid >> 3) & 7;
    const int g  = tid >> 6;          // wave index, uniform

    float d0 = 0.f, d1 = 0.f;
    float cr[7], ci[7];
    #pragma unroll
    for (int p = 0; p < 7; ++p) { cr[p] = 0.f; ci[p] = 0.f; }

    {
        const float* rrow = g_r + base + (k << 9);
        #pragma unroll 2
        for (int i = 0; i < 16; ++i) {
            const int t = (i << 5) + (tl << 2);
            const float4 rv = *(const float4*)&rrow[t];   // global (hoistable)
            float4 xr4[8], xi4[8];
            #pragma unroll
            for (int n = 0; n < 8; ++n) {
                xr4[n] = *(const float4*)&s_xr[n][t];
                xi4[n] = *(const float4*)&s_xi[n][t];
            }
            if      (g == 0) { PA_G0(x) PA_G0(y) PA_G0(z) PA_G0(w) }
            else if (g == 1) { PA_G1(x) PA_G1(y) PA_G1(z) PA_G1(w) }
            else if (g == 2) { PA_G2(x) PA_G2(y) PA_G2(z) PA_G2(w) }
            else             { PA_G3(x) PA_G3(y) PA_G3(z) PA_G3(w) }
        }
    }

    // reduce across the 8 t-lanes of each (g,k): xor 1,2,4 stay in-group
    #pragma unroll
    for (int off = 1; off < 8; off <<= 1) {
        d0 += __shfl_xor(d0, off, 64);
        d1 += __shfl_xor(d1, off, 64);
        #pragma unroll
        for (int p = 0; p < 7; ++p) {
            cr[p] += __shfl_xor(cr[p], off, 64);
            ci[p] += __shfl_xor(ci[p], off, 64);
        }
    }

    if (tl == 0) {
        const float invT = 1.0f / 512.0f;
        if (g == 0) {
            VSTD2(d0,0) VSTO2(0,0,1) VSTO2(1,0,2) VSTO2(2,0,3) VSTO2(3,0,4)
                        VSTO2(4,0,5) VSTO2(5,0,6) VSTO2(6,0,7)
            VSTD2(d1,7)
        } else if (g == 1) {
            VSTD2(d0,1) VSTO2(0,1,2) VSTO2(1,1,3) VSTO2(2,1,4) VSTO2(3,1,5)
                        VSTO2(4,1,6) VSTO2(5,1,7)
            VSTD2(d1,6) VSTO2(6,6,7)
        } else if (g == 2) {
            VSTD2(d0,2) VSTO2(0,2,3) VSTO2(1,2,4) VSTO2(2,2,5) VSTO2(3,2,6)
                        VSTO2(4,2,7)
            VSTD2(d1,5) VSTO2(5,5,6) VSTO2(6,5,7)
        } else {
            VSTD2(d0,3) VSTO2(0,3,4) VSTO2(1,3,5) VSTO2(2,3,6) VSTO2(3,3,7)
            VSTD2(d1,4) VSTO2(4,4,5) VSTO2(5,4,6) VSTO2(6,4,7)
        }
    }
    __syncthreads();

    // ---- diag fix + phase B: SINGLE WAVE; waves 1-3 exit (frees the SIMD) ----
    if (tid < 64) {
        {
            const int kq = tid >> 3, mq = tid & 7;
            const float dv = s_V[kq][mq][mq].x;
            float tr = dv;
            #pragma unroll
            for (int off = 1; off < 8; off <<= 1) tr += __shfl_xor(tr, off, 64);
            s_V[kq][mq][mq].x = dv + fmaxf(tr, 1.0f) * 1e-6f;
        }
        const int kp = tid >> 3, mm = tid & 7;
        float vRr[8], vRi[8];
        #pragma unroll
        for (int n = 0; n < 8; ++n) {
            const float2 V = s_V[kp][mm][n];
            vRr[n] = V.x; vRi[n] = V.y;
        }
        const float2 Q0 = s_Q[kp][mm];
        float qre = Q0.x, qim = Q0.y;

        #pragma unroll
        for (int step = 0; step < 16; ++step) {
            const int kk = step & 7;
            float qnr[8], qni[8];
            #pragma unroll
            for (int n = 0; n < 8; ++n) {
                qnr[n] = __shfl(qre, (kk<<3)+n, 64);
                qni[n] = __shfl(qim, (kk<<3)+n, 64);
            }
            const float qmr = __shfl(qre, (kk<<3)+mm, 64);
            const float qmi = __shfl(qim, (kk<<3)+mm, 64);

            float vqr = 0.f, vqi = 0.f;
            #pragma unroll
            for (int n = 0; n < 8; ++n) {
                vqr += vRr[n]*qnr[n] + vRi[n]*qni[n];   // V * conj(q)
                vqi += vRi[n]*qnr[n] - vRr[n]*qni[n];
            }
            float p   = qmr*vqr - qmi*vqi;              // Re(q_m * Vq_m)
            float tre = qre*vqr - qim*vqi;              // Q_own * Vq_own
            float tim = qre*vqi + qim*vqr;
            #pragma unroll
            for (int off = 1; off < 8; off <<= 1) {
                p   += __shfl_xor(p,   off, 64);
                tre += __shfl_xor(tre, off, 64);
                tim += __shfl_xor(tim, off, 64);
            }
            const float qvq = fmaxf(p, 1e-6f);
            float vr_, vi_;
            if (kp == kk) { vr_ = 1.0f - rsqrtf(qvq); vi_ = 0.f; }
            else { const float inv = 1.0f / qvq; vr_ = tre*inv; vi_ = tim*inv; }
            qre -= vr_*qmr - vi_*qmi;
            qim -= vr_*qmi + vi_*qmr;
        }

        d_Qc[(size_t)bf*64 + tid] = make_float2(qre, qim);   // full complex for iss_xt
        if (qmode == 2) {
            g_out[(size_t)bf*128 + tid*2]     = qre;
            g_out[(size_t)bf*128 + tid*2 + 1] = qim;
        } else {
            g_out[(size_t)bf*64 + tid] = qre;   // harness stores Q.real only
        }
    }
}

// iss_xt: pure streaming (exact r17). 128 threads per bf; 4 consecutive t per
// thread (float4 loads/stores, coalesced); Q from d_Qc; per-bf partial sums.
__global__ void iss_xt(
    const float* __restrict__ g_xre,
    const float* __restrict__ g_xim,
    float* __restrict__ g_out,
    const int xt_off)
{
    __shared__ float2 s_Q[8][8];
    __shared__ float  sp[2];

    const int tid = threadIdx.x;
    const int bf  = blockIdx.x;
    const size_t base = (size_t)bf * 4096;
    const float* xre = g_xre + base;
    const float* xim = g_xim + base;

    if (tid < 64)
        s_Q[tid>>3][tid&7] = d_Qc[(size_t)bf*64 + tid];
    __syncthreads();

    float* out_xt = g_out + xt_off;
    const int t0 = tid << 2;               // 4 consecutive t
    float4 xr4[8], xi4[8];
    #pragma unroll
    for (int n = 0; n < 8; ++n) {
        xr4[n] = *(const float4*)&xre[(n << 9) + t0];
        xi4[n] = *(const float4*)&xim[(n << 9) + t0];
    }
    float lsum = 0.f;
    #pragma unroll
    for (int m = 0; m < 8; ++m) {
        float2 qv[8];
        #pragma unroll
        for (int n = 0; n < 8; ++n) qv[n] = s_Q[m][n];   // broadcast (free)
        float a0=0.f,b0=0.f,a1=0.f,b1=0.f,a2=0.f,b2=0.f,a3=0.f,b3=0.f;
        #pragma unroll
        for (int n = 0; n < 8; ++n) {
            const float qr = qv[n].x, qi = qv[n].y;
            a0 += qr*xr4[n].x - qi*xi4[n].x;  b0 += qr*xi4[n].x + qi*xr4[n].x;
            a1 += qr*xr4[n].y - qi*xi4[n].y;  b1 += qr*xi4[n].y + qi*xr4[n].y;
            a2 += qr*xr4[n].z - qi*xi4[n].z;  b2 += qr*xi4[n].z + qi*xr4[n].z;
            a3 += qr*xr4[n].w - qi*xi4[n].w;  b3 += qr*xi4[n].w + qi*xr4[n].w;
        }
        float4 pw;
        pw.x = a0*a0 + b0*b0;  pw.y = a1*a1 + b1*b1;
        pw.z = a2*a2 + b2*b2;  pw.w = a3*a3 + b3*b3;
        *(float4*)&out_xt[base + (m << 9) + t0] = pw;
        lsum += pw.x + pw.y + pw.z + pw.w;
    }
    #pragma unroll
    for (int off = 32; off >= 1; off >>= 1) lsum += __shfl_xor(lsum, off, 64);
    if ((tid & 63) == 0) sp[tid >> 6] = lsum;
    __syncthreads();
    if (tid == 0) d_partials[bf] = sp[0] + sp[1];
}

// iss_norm: r17's normalize, with the scale reduction FOLDED IN (saves the
// iss_scale launch). Each block redundantly reduces the 4104 partials from
// L2 (~16 KB/block, ~2 us chip-wide): 8 b's x 32 lanes, half-wave shfl tree.
__global__ __launch_bounds__(256) void iss_norm(
    float* __restrict__ g_out,
    const int nq4,     // Q region in float4s  (= xt_off/4)
    const int qb4,     // float4s per batch in Q region
    const int nt4)     // total float4s (= out_size/4)
{
    __shared__ float s_scale[8];
    const int tid = threadIdx.x;
    {
        const int b = tid >> 5, li = tid & 31;
        float s = 0.f;
        for (int i = li; i < 513; i += 32) s += d_partials[b*513 + i];
        #pragma unroll
        for (int off = 1; off < 32; off <<= 1) s += __shfl_xor(s, off, 64);
        if (li == 0) s_scale[b] = s / (513.0f * 8.0f * 512.0f);
    }
    __syncthreads();

    float4* o4 = (float4*)g_out;
    for (int i = blockIdx.x*256 + tid; i < nt4; i += gridDim.x*256) {
        float s;
        if (i < nq4) {
            const int b = i / qb4;
            s = rsqrtf(fmaxf(s_scale[b], 1e-6f));
        } else {
            const int j = i - nq4;
            const int b = j / 525312;          // xt float4s per batch
            s = 1.0f / s_scale[b];
        }
        float4 v = o4[i];
        v.x *= s; v.y *= s; v.z *= s; v.w *= s;
        o4[i] = v;
    }
}

extern "C" void kernel_launch(void* const* d_in, const int* in_sizes, int n_in,
                              void* d_out, int out_size, void* d_ws, size_t ws_size,
                              hipStream_t stream) {
    const float* r   = (const float*)d_in[0];
    const float* xre = (const float*)d_in[1];
    const float* xim = (const float*)d_in[2];
    const float* Qre = (const float*)d_in[3];
    const float* Qim = (const float*)d_in[4];
    float* out = (float*)d_out;

    const int q_floats = out_size - XT_FLOATS;
    const int qmode  = (q_floats >= 525312) ? 2 : 1;  // empirically qmode=1 (r13)
    const int xt_off = (qmode == 2) ? 525312 : 262656;
    const int nq4 = xt_off / 4;
    const int qb4 = xt_off / (4 * 8);
    const int nt4 = nq4 + XT_FLOATS / 4;

    iss_cov <<<NBF, 256, 0, stream>>>(r, xre, xim, Qre, Qim, out, qmode);
    iss_xt  <<<NBF, 128, 0, stream>>>(xre, xim, out, xt_off);
    iss_norm<<<4096,256, 0, stream>>>(out, nq4, qb4, nt4);
}

// Round 21
// 198.476 us; speedup vs baseline: 1.0110x; 1.0110x over previous
//
#include <hip/hip_runtime.h>
#include <math.h>

#define NBF 4104             // B*F = 8*513
#define XT_FLOATS 16809984   // 8*513*8*512

// Static device scratch; fully overwritten before read each call -> deterministic.
__device__ float  d_partials[NBF];
__device__ float2 d_Qc[NBF * 64];   // full complex Q (g_out only holds Re in qmode=1)

// Phase-A macros over float4 components (r17's proven form: wave g owns row-pair
// {g,7-g}, 9 Hermitian entries, 16 accumulator floats -> VGPR 68, no spill).
#define PA_CROSS(P,N,C) cr[P] += ar*xr4[N].C + ai*xi4[N].C; \
                        ci[P] += ai*xr4[N].C - ar*xi4[N].C;

#define PA_G0(C) { const float rw = fmaxf(rv.C, 1e-3f); float ar, ai;          \
    ar = rw*xr4[0].C; ai = rw*xi4[0].C; d0 += ar*xr4[0].C + ai*xi4[0].C;       \
    PA_CROSS(0,1,C) PA_CROSS(1,2,C) PA_CROSS(2,3,C) PA_CROSS(3,4,C)            \
    PA_CROSS(4,5,C) PA_CROSS(5,6,C) PA_CROSS(6,7,C)                            \
    ar = rw*xr4[7].C; ai = rw*xi4[7].C; d1 += ar*xr4[7].C + ai*xi4[7].C; }

#define PA_G1(C) { const float rw = fmaxf(rv.C, 1e-3f); float ar, ai;          \
    ar = rw*xr4[1].C; ai = rw*xi4[1].C; d0 += ar*xr4[1].C + ai*xi4[1].C;       \
    PA_CROSS(0,2,C) PA_CROSS(1,3,C) PA_CROSS(2,4,C) PA_CROSS(3,5,C)            \
    PA_CROSS(4,6,C) PA_CROSS(5,7,C)                                            \
    ar = rw*xr4[6].C; ai = rw*xi4[6].C; d1 += ar*xr4[6].C + ai*xi4[6].C;       \
    PA_CROSS(6,7,C) }

#define PA_G2(C) { const float rw = fmaxf(rv.C, 1e-3f); float ar, ai;          \
    ar = rw*xr4[2].C; ai = rw*xi4[2].C; d0 += ar*xr4[2].C + ai*xi4[2].C;       \
    PA_CROSS(0,3,C) PA_CROSS(1,4,C) PA_CROSS(2,5,C) PA_CROSS(3,6,C)            \
    PA_CROSS(4,7,C)                                                            \
    ar = rw*xr4[5].C; ai = rw*xi4[5].C; d1 += ar*xr4[5].C + ai*xi4[5].C;       \
    PA_CROSS(5,6,C) PA_CROSS(6,7,C) }

#define PA_G3(C) { const float rw = fmaxf(rv.C, 1e-3f); float ar, ai;          \
    ar = rw*xr4[3].C; ai = rw*xi4[3].C; d0 += ar*xr4[3].C + ai*xi4[3].C;       \
    PA_CROSS(0,4,C) PA_CROSS(1,5,C) PA_CROSS(2,6,C) PA_CROSS(3,7,C)            \
    ar = rw*xr4[4].C; ai = rw*xi4[4].C; d1 += ar*xr4[4].C + ai*xi4[4].C;       \
    PA_CROSS(4,5,C) PA_CROSS(5,6,C) PA_CROSS(6,7,C) }

#define VSTD2(D,M)  s_V[k][M][M] = make_float2((D)*invT, 0.f);
#define VSTO2(P,M,N){ const float vr=cr[P]*invT, vi=ci[P]*invT;  \
                      s_V[k][M][N] = make_float2(vr,  vi);       \
                      s_V[k][N][M] = make_float2(vr, -vi); }

// (256,3): cap 85 >= natural 68 -> no spill; guarantees 3+ blocks/CU.
// Occupancy-null results (r10/r11/r15) were on the OLD float2 structure; the
// float4+LDS structure is ds_read-latency-stalled at 2 waves/SIMD — the one
// untested cell. If this nulls too, the kernel is at its issue/latency
// equilibrium (roofline for this structure).
__global__ __launch_bounds__(256, 3) void iss_cov(
    const float* __restrict__ g_r,
    const float* __restrict__ g_xre,
    const float* __restrict__ g_xim,
    const float* __restrict__ g_Qre,
    const float* __restrict__ g_Qim,
    float* __restrict__ g_out,
    const int qmode)
{
    __shared__ float  s_xr[8][512];    // 16 KB
    __shared__ float  s_xi[8][512];    // 16 KB
    __shared__ float2 s_V[8][8][9];    // padded row stride
    __shared__ float2 s_Q[8][8];

    const int tid = threadIdx.x;
    const int bf  = blockIdx.x;
    const size_t base = (size_t)bf * 4096;

    const float* xre = g_xre + base;
    const float* xim = g_xim + base;

    // ---- stage x into LDS (float4 loads + b128 writes, fully coalesced) ----
    {
        const float4* xr4g = (const float4*)xre;
        const float4* xi4g = (const float4*)xim;
        float4* sxr4 = (float4*)&s_xr[0][0];
        float4* sxi4 = (float4*)&s_xi[0][0];
        #pragma unroll
        for (int i = 0; i < 4; ++i) {
            const int idx = tid + (i << 8);
            sxr4[idx] = xr4g[idx];
            sxi4[idx] = xi4g[idx];
        }
        if (tid < 64)
            s_Q[tid>>3][tid&7] = make_float2(g_Qre[(size_t)bf*64 + tid],
                                             g_Qim[(size_t)bf*64 + tid]);
    }
    __syncthreads();

    // ---- phase A: V[k] = (1/T) sum_t max(r,1e-3) x x^H -------------------
    const int tl = tid & 7;
    const int k  = (tid >> 3) & 7;
    const int g  = tid >> 6;          // wave index, uniform

    float d0 = 0.f, d1 = 0.f;
    float cr[7], ci[7];
    #pragma unroll
    for (int p = 0; p < 7; ++p) { cr[p] = 0.f; ci[p] = 0.f; }

    {
        const float* rrow = g_r + base + (k << 9);
        #pragma unroll 2
        for (int i = 0; i < 16; ++i) {
            const int t = (i << 5) + (tl << 2);
            const float4 rv = *(const float4*)&rrow[t];   // global (hoistable)
            float4 xr4[8], xi4[8];
            #pragma unroll
            for (int n = 0; n < 8; ++n) {
                xr4[n] = *(const float4*)&s_xr[n][t];
                xi4[n] = *(const float4*)&s_xi[n][t];
            }
            if      (g == 0) { PA_G0(x) PA_G0(y) PA_G0(z) PA_G0(w) }
            else if (g == 1) { PA_G1(x) PA_G1(y) PA_G1(z) PA_G1(w) }
            else if (g == 2) { PA_G2(x) PA_G2(y) PA_G2(z) PA_G2(w) }
            else             { PA_G3(x) PA_G3(y) PA_G3(z) PA_G3(w) }
        }
    }

    // reduce across the 8 t-lanes of each (g,k): xor 1,2,4 stay in-group
    #pragma unroll
    for (int off = 1; off < 8; off <<= 1) {
        d0 += __shfl_xor(d0, off, 64);
        d1 += __shfl_xor(d1, off, 64);
        #pragma unroll
        for (int p = 0; p < 7; ++p) {
            cr[p] += __shfl_xor(cr[p], off, 64);
            ci[p] += __shfl_xor(ci[p], off, 64);
        }
    }

    if (tl == 0) {
        const float invT = 1.0f / 512.0f;
        if (g == 0) {
            VSTD2(d0,0) VSTO2(0,0,1) VSTO2(1,0,2) VSTO2(2,0,3) VSTO2(3,0,4)
                        VSTO2(4,0,5) VSTO2(5,0,6) VSTO2(6,0,7)
            VSTD2(d1,7)
        } else if (g == 1) {
            VSTD2(d0,1) VSTO2(0,1,2) VSTO2(1,1,3) VSTO2(2,1,4) VSTO2(3,1,5)
                        VSTO2(4,1,6) VSTO2(5,1,7)
            VSTD2(d1,6) VSTO2(6,6,7)
        } else if (g == 2) {
            VSTD2(d0,2) VSTO2(0,2,3) VSTO2(1,2,4) VSTO2(2,2,5) VSTO2(3,2,6)
                        VSTO2(4,2,7)
            VSTD2(d1,5) VSTO2(5,5,6) VSTO2(6,5,7)
        } else {
            VSTD2(d0,3) VSTO2(0,3,4) VSTO2(1,3,5) VSTO2(2,3,6) VSTO2(3,3,7)
            VSTD2(d1,4) VSTO2(4,4,5) VSTO2(5,4,6) VSTO2(6,4,7)
        }
    }
    __syncthreads();

    // ---- diag fix + phase B: SINGLE WAVE; waves 1-3 exit (frees the SIMD) ----
    if (tid < 64) {
        {
            const int kq = tid >> 3, mq = tid & 7;
            const float dv = s_V[kq][mq][mq].x;
            float tr = dv;
            #pragma unroll
            for (int off = 1; off < 8; off <<= 1) tr += __shfl_xor(tr, off, 64);
            s_V[kq][mq][mq].x = dv + fmaxf(tr, 1.0f) * 1e-6f;
        }
        const int kp = tid >> 3, mm = tid & 7;
        float vRr[8], vRi[8];
        #pragma unroll
        for (int n = 0; n < 8; ++n) {
            const float2 V = s_V[kp][mm][n];
            vRr[n] = V.x; vRi[n] = V.y;
        }
        const float2 Q0 = s_Q[kp][mm];
        float qre = Q0.x, qim = Q0.y;

        #pragma unroll
        for (int step = 0; step < 16; ++step) {
            const int kk = step & 7;
            float qnr[8], qni[8];
            #pragma unroll
            for (int n = 0; n < 8; ++n) {
                qnr[n] = __shfl(qre, (kk<<3)+n, 64);
                qni[n] = __shfl(qim, (kk<<3)+n, 64);
            }
            const float qmr = __shfl(qre, (kk<<3)+mm, 64);
            const float qmi = __shfl(qim, (kk<<3)+mm, 64);

            float vqr = 0.f, vqi = 0.f;
            #pragma unroll
            for (int n = 0; n < 8; ++n) {
                vqr += vRr[n]*qnr[n] + vRi[n]*qni[n];   // V * conj(q)
                vqi += vRi[n]*qnr[n] - vRr[n]*qni[n];
            }
            float p   = qmr*vqr - qmi*vqi;              // Re(q_m * Vq_m)
            float tre = qre*vqr - qim*vqi;              // Q_own * Vq_own
            float tim = qre*vqi + qim*vqr;
            #pragma unroll
            for (int off = 1; off < 8; off <<= 1) {
                p   += __shfl_xor(p,   off, 64);
                tre += __shfl_xor(tre, off, 64);
                tim += __shfl_xor(tim, off, 64);
            }
            const float qvq = fmaxf(p, 1e-6f);
            float vr_, vi_;
            if (kp == kk) { vr_ = 1.0f - rsqrtf(qvq); vi_ = 0.f; }
            else { const float inv = 1.0f / qvq; vr_ = tre*inv; vi_ = tim*inv; }
            qre -= vr_*qmr - vi_*qmi;
            qim -= vr_*qmi + vi_*qmr;
        }

        d_Qc[(size_t)bf*64 + tid] = make_float2(qre, qim);   // full complex for iss_xt
        if (qmode == 2) {
            g_out[(size_t)bf*128 + tid*2]     = qre;
            g_out[(size_t)bf*128 + tid*2 + 1] = qim;
        } else {
            g_out[(size_t)bf*64 + tid] = qre;   // harness stores Q.real only
        }
    }
}

// iss_xt: pure streaming (exact r17). 128 threads per bf; 4 consecutive t per
// thread (float4 loads/stores, coalesced); Q from d_Qc; per-bf partial sums.
__global__ void iss_xt(
    const float* __restrict__ g_xre,
    const float* __restrict__ g_xim,
    float* __restrict__ g_out,
    const int xt_off)
{
    __shared__ float2 s_Q[8][8];
    __shared__ float  sp[2];

    const int tid = threadIdx.x;
    const int bf  = blockIdx.x;
    const size_t base = (size_t)bf * 4096;
    const float* xre = g_xre + base;
    const float* xim = g_xim + base;

    if (tid < 64)
        s_Q[tid>>3][tid&7] = d_Qc[(size_t)bf*64 + tid];
    __syncthreads();

    float* out_xt = g_out + xt_off;
    const int t0 = tid << 2;               // 4 consecutive t
    float4 xr4[8], xi4[8];
    #pragma unroll
    for (int n = 0; n < 8; ++n) {
        xr4[n] = *(const float4*)&xre[(n << 9) + t0];
        xi4[n] = *(const float4*)&xim[(n << 9) + t0];
    }
    float lsum = 0.f;
    #pragma unroll
    for (int m = 0; m < 8; ++m) {
        float2 qv[8];
        #pragma unroll
        for (int n = 0; n < 8; ++n) qv[n] = s_Q[m][n];   // broadcast (free)
        float a0=0.f,b0=0.f,a1=0.f,b1=0.f,a2=0.f,b2=0.f,a3=0.f,b3=0.f;
        #pragma unroll
        for (int n = 0; n < 8; ++n) {
            const float qr = qv[n].x, qi = qv[n].y;
            a0 += qr*xr4[n].x - qi*xi4[n].x;  b0 += qr*xi4[n].x + qi*xr4[n].x;
            a1 += qr*xr4[n].y - qi*xi4[n].y;  b1 += qr*xi4[n].y + qi*xr4[n].y;
            a2 += qr*xr4[n].z - qi*xi4[n].z;  b2 += qr*xi4[n].z + qi*xr4[n].z;
            a3 += qr*xr4[n].w - qi*xi4[n].w;  b3 += qr*xi4[n].w + qi*xr4[n].w;
        }
        float4 pw;
        pw.x = a0*a0 + b0*b0;  pw.y = a1*a1 + b1*b1;
        pw.z = a2*a2 + b2*b2;  pw.w = a3*a3 + b3*b3;
        *(float4*)&out_xt[base + (m << 9) + t0] = pw;
        lsum += pw.x + pw.y + pw.z + pw.w;
    }
    #pragma unroll
    for (int off = 32; off >= 1; off >>= 1) lsum += __shfl_xor(lsum, off, 64);
    if ((tid & 63) == 0) sp[tid >> 6] = lsum;
    __syncthreads();
    if (tid == 0) d_partials[bf] = sp[0] + sp[1];
}

// iss_norm: normalize with the scale reduction folded in (saves a launch).
__global__ __launch_bounds__(256) void iss_norm(
    float* __restrict__ g_out,
    const int nq4,     // Q region in float4s  (= xt_off/4)
    const int qb4,     // float4s per batch in Q region
    const int nt4)     // total float4s (= out_size/4)
{
    __shared__ float s_scale[8];
    const int tid = threadIdx.x;
    {
        const int b = tid >> 5, li = tid & 31;
        float s = 0.f;
        for (int i = li; i < 513; i += 32) s += d_partials[b*513 + i];
        #pragma unroll
        for (int off = 1; off < 32; off <<= 1) s += __shfl_xor(s, off, 64);
        if (li == 0) s_scale[b] = s / (513.0f * 8.0f * 512.0f);
    }
    __syncthreads();

    float4* o4 = (float4*)g_out;
    for (int i = blockIdx.x*256 + tid; i < nt4; i += gridDim.x*256) {
        float s;
        if (i < nq4) {
            const int b = i / qb4;
            s = rsqrtf(fmaxf(s_scale[b], 1e-6f));
        } else {
            const int j = i - nq4;
            const int b = j / 525312;          // xt float4s per batch
            s = 1.0f / s_scale[b];
        }
        float4 v = o4[i];
        v.x *= s; v.y *= s; v.z *= s; v.w *= s;
        o4[i] = v;
    }
}

extern "C" void kernel_launch(void* const* d_in, const int* in_sizes, int n_in,
                              void* d_out, int out_size, void* d_ws, size_t ws_size,
                              hipStream_t stream) {
    const float* r   = (const float*)d_in[0];
    const float* xre = (const float*)d_in[1];
    const float* xim = (const float*)d_in[2];
    const float* Qre = (const float*)d_in[3];
    const float* Qim = (const float*)d_in[4];
    float* out = (float*)d_out;

    const int q_floats = out_size - XT_FLOATS;
    const int qmode  = (q_floats >= 525312) ? 2 : 1;  // empirically qmode=1 (r13)
    const int xt_off = (qmode == 2) ? 525312 : 262656;
    const int nq4 = xt_off / 4;
    const int qb4 = xt_off / (4 * 8);
    const int nt4 = nq4 + XT_FLOATS / 4;

    iss_cov <<<NBF, 256, 0, stream>>>(r, xre, xim, Qre, Qim, out, qmode);
    iss_xt  <<<NBF, 128, 0, stream>>>(xre, xim, out, xt_off);
    iss_norm<<<4096,256, 0, stream>>>(out, nq4, qb4, nt4);
}